// Round 8
// baseline (362.859 us; speedup 1.0000x reference)
//
#include <hip/hip_runtime.h>
#include <hip/hip_bf16.h>

// MLA forward. Storage fp32 in/out; internal pipeline bf16 MFMA, fp32 accum.
// R8 changes vs R7 (353.7us):
//  - GEMMs: 8-wave blocks (512 thr), same 128^2 tile, wave-tile 32x64
//    (4Mx2N). Same math order per element; waves/SIMD 2->4 at our small
//    grids (384/1408/512 blocks) -- m102 showed the 4-wave structure
//    collapses to ~320-550 TF there from TLP starvation.
//  - RoPE fused into GEMM epilogues (pair (j,j+8) = lanes l16^8 in the same
//    nt-block -> one shfl_xor + trig). k_rot fp32 written directly from the
//    proj1 kr segment (one less rounding). rope kernel deleted; 6->5 launches.
//  - attn unchanged from R7 (verified 73.5us).
#define B_   2
#define S_   2048
#define E_   2048
#define H_   16
#define DH_  128
#define DR_  32
#define SP_  96
#define C_   512
#define M_   (B_ * S_)   // 4096 rows

#define LOG2E 1.4426950408889634f

typedef __attribute__((ext_vector_type(8))) short short8;
typedef __attribute__((ext_vector_type(4))) float floatx4;

__device__ __forceinline__ float bfu(unsigned short u) {
  return __uint_as_float((unsigned)u << 16);
}
__device__ __forceinline__ unsigned short f2bf(float f) {
  unsigned u = __float_as_uint(f);
  return (unsigned short)((u + 0x7fff + ((u >> 16) & 1)) >> 16);  // RNE
}

// async global->LDS, 16B per lane. LDS dest: wave-uniform base + lane*16.
__device__ __forceinline__ void gload16(const void* g, void* l) {
  __builtin_amdgcn_global_load_lds(
      (const __attribute__((address_space(1))) void*)g,
      (__attribute__((address_space(3))) void*)l, 16, 0, 0);
}

// ---------- prep: fp32->bf16 h convert + all 8 weight transposes ----------
struct TEnt { const float* W; unsigned short* Wt; int K, N, ntiles, nx; };
struct TTab { TEnt e[8]; };

__global__ __launch_bounds__(256) void prep_kernel(
    const float* __restrict__ hsrc, unsigned short* __restrict__ hdst,
    TTab tab) {
  if (blockIdx.x < 8192) {  // f2bf path (block-uniform branch)
    size_t i = ((size_t)blockIdx.x * 256 + threadIdx.x) * 4;
    float4 v = *(const float4*)(hsrc + i);
    ushort4 w;
    w.x = f2bf(v.x); w.y = f2bf(v.y); w.z = f2bf(v.z); w.w = f2bf(v.w);
    *(ushort4*)(hdst + i) = w;
    return;
  }
  __shared__ unsigned short T[32][33];
  int rem = blockIdx.x - 8192;
  const float* W = nullptr; unsigned short* Wt = nullptr;
  int K = 0, N = 0, nx = 1;
  bool done = false;
#pragma unroll
  for (int j = 0; j < 8; j++) {   // constant-index select (stays in SGPRs)
    if (!done) {
      if (rem < tab.e[j].ntiles) {
        W = tab.e[j].W; Wt = tab.e[j].Wt;
        K = tab.e[j].K; N = tab.e[j].N; nx = tab.e[j].nx;
        done = true;
      } else {
        rem -= tab.e[j].ntiles;
      }
    }
  }
  int n0 = (rem % nx) * 32, k0 = (rem / nx) * 32;
  int t = threadIdx.x, lane = t & 31, grp = t >> 5;
#pragma unroll
  for (int p = 0; p < 4; p++) {
    int k = p * 8 + grp;
    T[lane][k] = f2bf(W[(size_t)(k0 + k) * N + n0 + lane]);
  }
  __syncthreads();
#pragma unroll
  for (int p = 0; p < 4; p++) {
    int n = p * 8 + grp;
    Wt[(size_t)(n0 + n) * K + k0 + lane] = T[n][lane];
  }
}

// ---------- bf16 MFMA GEMM core: 8 waves, 128^2 tile, 2-phase pipeline ----------
struct Seg {
  float* outF;
  unsigned short* outB;
  const float* bias;    // indexed by n_local
  const float* biasM;   // indexed by m (overrides bias)
  float* krotF;         // rope==1: fp32 k_rot out (idx m*512 + nl)
  int orow, chunk, gstride, obase, nstart, ileave, rope;
  float oscale;
};

__device__ __forceinline__ void gemm_body(
    const unsigned short* __restrict__ A, const unsigned short* __restrict__ W,
    int K, int bm, int bn, const Seg& sg) {
  __shared__ unsigned short As0[128 * 32];
  __shared__ unsigned short Bs0[128 * 32];
  __shared__ unsigned short As1[128 * 32];
  __shared__ unsigned short Bs1[128 * 32];
  int tid = threadIdx.x;
  int lane = tid & 63, wave = tid >> 6;          // 0..7
  int l16 = lane & 15, quad = lane >> 4;
  int wm = (wave & 3) * 32, wn = (wave >> 2) * 64;

  floatx4 acc[2][4];
#pragma unroll
  for (int mt = 0; mt < 2; mt++)
#pragma unroll
    for (int nt = 0; nt < 4; nt++) acc[mt][nt] = (floatx4){0.f, 0.f, 0.f, 0.f};

  // staging: 8 chunks of 1KB per operand; wave w stages chunk w of A and B.
  int srow = lane >> 2, scol = (lane & 3) * 8;
  const unsigned short* Ag = A + (size_t)(bm + wave * 16 + srow) * K + scol;
  const unsigned short* Bg = W + (size_t)(bn + wave * 16 + srow) * K + scol;
  int lo = wave * 512;

#define GSTAGE(kk, Asb, Bsb) do {      \
    gload16(Ag + (kk), &Asb[lo]);      \
    gload16(Bg + (kk), &Bsb[lo]); } while (0)

#define GCOMPUTE(Asb, Bsb) do {                                            \
    short8 af[2], bfv[4];                                                  \
    _Pragma("unroll")                                                      \
    for (int mt = 0; mt < 2; mt++)                                         \
      af[mt] = *(const short8*)&Asb[(wm + mt * 16 + l16) * 32 + quad * 8]; \
    _Pragma("unroll")                                                      \
    for (int nt = 0; nt < 4; nt++)                                         \
      bfv[nt] = *(const short8*)&Bsb[(wn + nt * 16 + l16) * 32 + quad * 8];\
    _Pragma("unroll")                                                      \
    for (int mt = 0; mt < 2; mt++)                                         \
      _Pragma("unroll")                                                    \
      for (int nt = 0; nt < 4; nt++)                                       \
        acc[mt][nt] = __builtin_amdgcn_mfma_f32_16x16x32_bf16(             \
            af[mt], bfv[nt], acc[mt][nt], 0, 0, 0); } while (0)

  GSTAGE(0, As0, Bs0);
  __syncthreads();
  for (int k0 = 0; k0 < K; k0 += 64) {
    GSTAGE(k0 + 32, As1, Bs1);
    GCOMPUTE(As0, Bs0);
    __syncthreads();
    if (k0 + 64 < K) GSTAGE(k0 + 64, As0, Bs0);
    GCOMPUTE(As1, Bs1);
    __syncthreads();
  }
#undef GSTAGE
#undef GCOMPUTE

  // C/D layout: D[row=quad*4+r][col=l16]
#pragma unroll
  for (int mt = 0; mt < 2; mt++) {
    int m0 = bm + wm + mt * 16 + quad * 4;
    float bm4[4] = {0.f, 0.f, 0.f, 0.f};
    if (sg.biasM) {
#pragma unroll
      for (int r = 0; r < 4; r++) bm4[r] = sg.biasM[m0 + r];
    }
#pragma unroll
    for (int nt = 0; nt < 4; nt++) {
      int n = bn + wn + nt * 16 + l16;
      int nl = n - sg.nstart;
      float bv = sg.biasM ? 0.f : sg.bias[nl];
      int ncol = sg.obase + (nl / sg.chunk) * sg.gstride + (nl % sg.chunk);
      if (sg.ileave)  // 32-wide k-interleave (attn V: phys 2k,2k+1 = k, k+16)
        ncol = (ncol & ~31) | ((ncol & 15) << 1) | ((ncol >> 4) & 1);
      bool rot_half = sg.rope && ((nl & 31) < 16);  // wave-uniform per nt
#pragma unroll
      for (int r = 0; r < 4; r++) {
        float val = (acc[mt][nt][r] + (sg.biasM ? bm4[r] : bv)) * sg.oscale;
        if (rot_half) {
          // rotation pair (j, j+8): partner at lane l16^8, same nt block
          int j = l16 & 7;
          int srw = (m0 + r) & (S_ - 1);
          float ang = ((float)srw / 40.0f) *
                      exp2f(-1.6609640474436813f * (float)j);
          float cc = cosf(ang), ss = sinf(ang);
          float part = __shfl_xor(val, 8);
          val = (l16 < 8) ? (val * cc - part * ss) : (val * cc + part * ss);
        }
        if (sg.rope == 1 && sg.krotF)
          sg.krotF[(size_t)(m0 + r) * (H_ * DR_) + nl] = val;
        size_t idx = (size_t)(m0 + r) * sg.orow + ncol;
        if (sg.outF) sg.outF[idx] = val;
        if (sg.outB) sg.outB[idx] = f2bf(val);
      }
    }
  }
}

// generic multi-segment GEMM (proj1, out-proj)
__global__ __launch_bounds__(512) void mfma_gemm(
    const unsigned short* __restrict__ A, const unsigned short* __restrict__ Wt,
    Seg s0, Seg s1, Seg s2, int K) {
  // XCD swizzle (bijective; nwg % 8 == 0 at every call site)
  int gx = gridDim.x;
  int nwg = gx * gridDim.y;
  int flat = blockIdx.y * gx + blockIdx.x;
  int w = (flat & 7) * (nwg >> 3) + (flat >> 3);
  int by = w / gx, bx = w - by * gx;
  int bm = by * 128, bn = bx * 128;
  Seg sg = (bn >= s2.nstart) ? s2 : ((bn >= s1.nstart) ? s1 : s0);
  gemm_body(A, Wt, K, bm, bn, sg);
}

// fused K=512 GEMM trio: uk (384 blk) | V^T (512 blk) | proj2 (512 blk)
__global__ __launch_bounds__(512) void fused_gemm3(
    const unsigned short* __restrict__ ckv, const unsigned short* __restrict__ cq,
    const unsigned short* __restrict__ wuk, const unsigned short* __restrict__ wuv,
    const unsigned short* __restrict__ wuq,
    unsigned short* __restrict__ kbf, unsigned short* __restrict__ vtbf,
    unsigned short* __restrict__ qbf,
    const float* __restrict__ b_uk, const float* __restrict__ b_uv,
    const float* __restrict__ b_uq, const float* __restrict__ b_qr,
    float qscale) {
  int flat = blockIdx.x;                      // 0..1407
  int w = (flat & 7) * 176 + (flat >> 3);     // XCD swizzle (1408/8 = 176)
  const unsigned short* A; const unsigned short* W;
  int bm, bn;
  Seg sg;
  sg.outF = nullptr; sg.oscale = 1.f; sg.ileave = 0; sg.nstart = 0;
  sg.rope = 0; sg.krotF = nullptr;
  if (w < 384) {              // uk: c_kv @ W_uk -> k_bf (head remap)
    int by = w / 12, bx = w - by * 12;
    bm = by * 128; bn = bx * 128;
    A = ckv; W = wuk;
    sg.outB = kbf; sg.bias = b_uk; sg.biasM = nullptr;
    sg.orow = 2048; sg.chunk = SP_; sg.gstride = DH_; sg.obase = 0;
  } else if (w < 896) {       // V^T: W_uv^T @ c_kv^T -> vt_bf (interleaved)
    int w2 = w - 384;
    int by = w2 >> 5, bx = w2 & 31;
    bm = by * 128; bn = bx * 128;
    A = wuv; W = ckv;
    sg.outB = vtbf; sg.bias = nullptr; sg.biasM = b_uv;
    sg.orow = M_; sg.chunk = M_; sg.gstride = M_; sg.obase = 0; sg.ileave = 1;
  } else {                    // proj2: c_q @ [W_uq|W_qr] -> q_bf, pre-scaled
    int w3 = w - 896;
    int by = w3 >> 4, bx = w3 & 15;
    bm = by * 128; bn = bx * 128;
    A = cq; W = wuq;
    sg.outB = qbf; sg.biasM = nullptr; sg.orow = 2048; sg.oscale = qscale;
    if (bn >= 1536) {
      sg.bias = b_qr; sg.chunk = DR_; sg.gstride = DH_; sg.obase = SP_;
      sg.nstart = 1536; sg.rope = 2;  // fused RoPE on q_rot
    } else {
      sg.bias = b_uq; sg.chunk = SP_; sg.gstride = DH_; sg.obase = 0;
    }
  }
  gemm_body(A, W, 512, bm, bn, sg);
}

// ---------- flash attention: merged pair, KVBLK=64, swizzled LDS ----------
// (R7 kernel verbatim.)
#define PST 72
__global__ __launch_bounds__(256, 2) void attn_kernel(
    const unsigned short* __restrict__ qf, const unsigned short* __restrict__ kf,
    const unsigned short* __restrict__ vt, unsigned short* __restrict__ ao) {
  __shared__ unsigned short Ks[2][64 * 128];   // row=k (256B), 16 slots
  __shared__ unsigned short Vs[2][128 * 64];   // row=d (128B), 8 slots
  __shared__ unsigned short Ps[4][16 * PST];

  int bid0 = blockIdx.x;            // 0..511
  int xcd  = bid0 & 7;
  int idx  = bid0 >> 3;             // 0..63 within XCD
  int r_   = idx >> 5;              // dispatch round (fills CUs once each)
  int q_   = idx & 31;
  int bh   = xcd * 4 + (q_ >> 3);   // 4 bh per XCD
  int jp   = r_ ? (15 - (q_ & 7)) : (q_ & 7);  // complementary per CU
  int h    = bh & 15;
  int b    = bh >> 4;
  int jjh  = 31 - jp;               // hi q-tile
  int jjl  = jp;                    // lo q-tile
  int q0h  = jjh << 6, q0l = jjl << 6;
  int nchunks = jjh + 1;            // 64-k chunks (17..32)

  int tid  = threadIdx.x;
  int wave = tid >> 6;
  int lane = tid & 63;
  int l16  = lane & 15;
  int quad = lane >> 4;
  int x7   = l16 & 7;

  // ---- staging maps (per thread: 4x16B K + 4x16B V per chunk) ----
  int krow = tid >> 2;              // 0..63
  int kst  = (tid & 3) * 4;         // starting 16B slot of 16
  int vrow = tid >> 1;              // 0..127
  int vst  = (tid & 1) * 4;         // starting 16B slot of 8
  const unsigned short* kg =
      kf + ((size_t)(b * S_ + krow)) * 2048 + h * 128 + kst * 8;
  const unsigned short* vg =
      vt + ((size_t)(h * 128 + vrow)) * 4096 + b * 2048 + vst * 8;
  // swizzled LDS write offsets (shorts)
  int kwl[4], vwl[4];
#pragma unroll
  for (int i = 0; i < 4; i++) {
    kwl[i] = krow * 128 + (((kst + i) ^ (krow & 7)) * 8);
    vwl[i] = vrow * 64  + (((vst + i) ^ (vrow & 7)) * 8);
  }

  // ---- Q fragments for both sides (pre-scaled in projection epilogue) ----
  short8 qfh[4], qfl[4];
  {
    const unsigned short* qb =
        qf + ((size_t)(b * S_ + q0h + wave * 16 + l16)) * 2048 + h * 128 + quad * 8;
#pragma unroll
    for (int c = 0; c < 4; c++) qfh[c] = *(const short8*)(qb + c * 32);
  }
  {
    const unsigned short* qb =
        qf + ((size_t)(b * S_ + q0l + wave * 16 + l16)) * 2048 + h * 128 + quad * 8;
#pragma unroll
    for (int c = 0; c < 4; c++) qfl[c] = *(const short8*)(qb + c * 32);
  }

  floatx4 OaccH[8], OaccL[8];
#pragma unroll
  for (int dt = 0; dt < 8; dt++) {
    OaccH[dt] = (floatx4){0.f, 0.f, 0.f, 0.f};
    OaccL[dt] = (floatx4){0.f, 0.f, 0.f, 0.f};
  }
  float lpH[4] = {0.f, 0.f, 0.f, 0.f};
  float lpL[4] = {0.f, 0.f, 0.f, 0.f};
  int qgh = q0h + wave * 16;        // base q row of this wave, hi side
  int qgl = q0l + wave * 16;

  // one side's compute vs staged chunk t in buf `cur`
#define SCOMPUTE(QF, OC, LP, QG, DIAG) do {                                   \
    const unsigned short* Kc = Ks[cur];                                       \
    const unsigned short* Vc = Vs[cur];                                       \
    floatx4 sv[4];                                                            \
    _Pragma("unroll")                                                         \
    for (int nt = 0; nt < 4; nt++) sv[nt] = (floatx4){0.f, 0.f, 0.f, 0.f};    \
    __builtin_amdgcn_s_setprio(1);                                            \
    _Pragma("unroll")                                                         \
    for (int nt = 0; nt < 4; nt++)                                            \
      _Pragma("unroll")                                                       \
      for (int c = 0; c < 4; c++) {                                           \
        short8 kfr = *(const short8*)&Kc[(nt * 16 + l16) * 128 +              \
                                         ((4 * c + quad) ^ x7) * 8];          \
        sv[nt] = __builtin_amdgcn_mfma_f32_16x16x32_bf16(QF[c], kfr, sv[nt],  \
                                                         0, 0, 0);            \
      }                                                                       \
    __builtin_amdgcn_s_setprio(0);                                            \
    unsigned short* P = Ps[wave];                                             \
    _Pragma("unroll")                                                         \
    for (int ks = 0; ks < 2; ks++)                                            \
      _Pragma("unroll")                                                       \
      for (int r = 0; r < 4; r++) {                                           \
        float p0 = exp2f(fminf(sv[2 * ks][r], 80.f));                         \
        float p1 = exp2f(fminf(sv[2 * ks + 1][r], 80.f));                     \
        if (DIAG) {                                                           \
          int q_r = QG + quad * 4 + r;                                        \
          int kc0 = kt0 + ks * 32 + l16;                                      \
          if (kc0 > q_r)      p0 = 0.f;                                       \
          if (kc0 + 16 > q_r) p1 = 0.f;                                       \
        }                                                                     \
        unsigned pk;                                                          \
        asm("v_cvt_pk_bf16_f32 %0, %1, %2" : "=v"(pk) : "v"(p0), "v"(p1));    \
        *(unsigned*)&P[(quad * 4 + r) * PST + ks * 32 + 2 * l16] = pk;        \
        LP[r] += p0 + p1;                                                     \
      }                                                                       \
    short8 pf0 = *(const short8*)&P[l16 * PST + quad * 8];                    \
    short8 pf1 = *(const short8*)&P[l16 * PST + 32 + quad * 8];               \
    __builtin_amdgcn_s_setprio(1);                                            \
    _Pragma("unroll")                                                         \
    for (int dt = 0; dt < 8; dt++) {                                          \
      short8 vf0 = *(const short8*)&Vc[(dt * 16 + l16) * 64 +                 \
                                       ((quad) ^ x7) * 8];                    \
      OC[dt] = __builtin_amdgcn_mfma_f32_16x16x32_bf16(pf0, vf0, OC[dt],      \
                                                       0, 0, 0);              \
      short8 vf1 = *(const short8*)&Vc[(dt * 16 + l16) * 64 +                 \
                                       ((4 + quad) ^ x7) * 8];                \
      OC[dt] = __builtin_amdgcn_mfma_f32_16x16x32_bf16(pf1, vf1, OC[dt],      \
                                                       0, 0, 0);              \
    }                                                                         \
    __builtin_amdgcn_s_setprio(0);                                            \
  } while (0)

  // ---- prologue: chunk 0 -> buf0; chunk 1 -> regs ----
  short8 kr[4], vr[4];
#pragma unroll
  for (int i = 0; i < 4; i++) {
    kr[i] = *(const short8*)(kg + i * 8);
    vr[i] = *(const short8*)(vg + i * 8);
  }
#pragma unroll
  for (int i = 0; i < 4; i++) {
    *(short8*)&Ks[0][kwl[i]] = kr[i];
    *(short8*)&Vs[0][vwl[i]] = vr[i];
  }
#pragma unroll
  for (int i = 0; i < 4; i++) {       // chunk 1 (nchunks >= 17)
    kr[i] = *(const short8*)(kg + 131072 + i * 8);
    vr[i] = *(const short8*)(vg + 64 + i * 8);
  }
  __syncthreads();

  int cur = 0;
  for (int t = 0; t < nchunks; t++) {
    // write chunk t+1 from regs into the other buffer
#pragma unroll
    for (int i = 0; i < 4; i++) {
      *(short8*)&Ks[cur ^ 1][kwl[i]] = kr[i];
      *(short8*)&Vs[cur ^ 1][vwl[i]] = vr[i];
    }
    // prefetch chunk t+2 (clamped)
    {
      int tf = (t + 2 < nchunks) ? t + 2 : nchunks - 1;
      const unsigned short* ksrc = kg + (size_t)tf * 131072;
      const unsigned short* vsrc = vg + tf * 64;
#pragma unroll
      for (int i = 0; i < 4; i++) {
        kr[i] = *(const short8*)(ksrc + i * 8);
        vr[i] = *(const short8*)(vsrc + i * 8);
      }
    }
    int kt0 = t << 6;
    SCOMPUTE(qfh, OaccH, lpH, qgh, (t == jjh));
    if (t <= jjl) SCOMPUTE(qfl, OaccL, lpL, qgl, (t == jjl));
    __syncthreads();
    cur ^= 1;
  }
#undef SCOMPUTE

  // ---- epilogue: l-reduction + store, both sides ----
#pragma unroll
  for (int side = 0; side < 2; side++) {
    floatx4* OC = side ? OaccL : OaccH;
    float*   LP = side ? lpL : lpH;
    int qg = (side ? qgl : qgh) + quad * 4;
    float linv[4];
#pragma unroll
    for (int r = 0; r < 4; r++) {
      float ls = LP[r];
#pragma unroll
      for (int sh = 1; sh < 16; sh <<= 1) ls += __shfl_xor(ls, sh);
      linv[r] = 1.0f / ls;
    }
#pragma unroll
    for (int r = 0; r < 4; r++) {
      unsigned short* dst =
          ao + ((size_t)(b * S_ + qg + r)) * 2048 + h * 128 + l16;
#pragma unroll
      for (int dt = 0; dt < 8; dt++) dst[dt * 16] = f2bf(OC[dt][r] * linv[r]);
    }
  }
}

static inline Seg mkseg(float* oF, unsigned short* oB, const float* bias,
                        const float* biasM, int orow, int chunk, int gstride,
                        int obase, int nstart, int ileave, float oscale,
                        int rope, float* krotF) {
  Seg s;
  s.outF = oF; s.outB = oB; s.bias = bias; s.biasM = biasM; s.krotF = krotF;
  s.orow = orow; s.chunk = chunk; s.gstride = gstride;
  s.obase = obase; s.nstart = nstart; s.ileave = ileave; s.rope = rope;
  s.oscale = oscale;
  return s;
}
static inline Seg segnone() {
  return mkseg(nullptr, nullptr, nullptr, nullptr, 1, 1, 1, 0, 0x7fffffff,
               0, 1.f, 0, nullptr);
}
static inline TEnt mktent(const float* W, unsigned short* Wt, int K, int N,
                          int ntiles, int nx) {
  TEnt e;
  e.W = W; e.Wt = Wt; e.K = K; e.N = N; e.ntiles = ntiles; e.nx = nx;
  return e;
}

extern "C" void kernel_launch(void* const* d_in, const int* in_sizes, int n_in,
                              void* d_out, int out_size, void* d_ws, size_t ws_size,
                              hipStream_t stream) {
  const float* h     = (const float*)d_in[0];
  const float* W_dkv = (const float*)d_in[1];
  const float* b_dkv = (const float*)d_in[2];
  const float* W_dq  = (const float*)d_in[3];
  const float* b_dq  = (const float*)d_in[4];
  const float* W_uk  = (const float*)d_in[5];
  const float* b_uk  = (const float*)d_in[6];
  const float* W_uv  = (const float*)d_in[7];
  const float* b_uv  = (const float*)d_in[8];
  const float* W_uq  = (const float*)d_in[9];
  const float* b_uq  = (const float*)d_in[10];
  const float* W_qr  = (const float*)d_in[11];
  const float* b_qr  = (const float*)d_in[12];
  const float* W_kr  = (const float*)d_in[13];
  const float* b_kr  = (const float*)d_in[14];
  const float* W_out = (const float*)d_in[15];
  const float* b_out = (const float*)d_in[16];

  float* out      = (float*)d_out;
  float* out_ckv  = out + (size_t)M_ * E_;
  float* out_krot = out_ckv + (size_t)M_ * C_;

  unsigned short* w16 = (unsigned short*)d_ws;
  unsigned short* h_bf   = w16;                 //  8,388,608
  unsigned short* q_bf   = w16 + 8388608;       //  8,388,608
  unsigned short* k_bf   = w16 + 16777216;      //  8,388,608
  unsigned short* vt_bf  = w16 + 25165824;      //  8,388,608  (V^T, s interleaved)
  unsigned short* ao_bf  = w16 + 33554432;      //  8,388,608
  unsigned short* ckv_bf = w16 + 41943040;      //  2,097,152
  unsigned short* cq_bf  = w16 + 44040192;      //  2,097,152
  // fused weight 1: rows [0,512)=W_dkv^T, [512,1024)=W_dq^T, [1024,1536)=W_kr^T
  unsigned short* Wt_dkv = w16 + 46137344;      //  1,048,576
  unsigned short* Wt_dq  = w16 + 47185920;      //  1,048,576 (= WtF1 + 512*2048)
  unsigned short* Wt_kr  = w16 + 48234496;      //  1,048,576 (= WtF1 + 1024*2048)
  unsigned short* Wt_uk  = w16 + 49283072;      //    786,432
  unsigned short* Wt_uv  = w16 + 50069504;      //  1,048,576
  // fused weight 2: rows [0,1536)=W_uq^T, [1536,2048)=W_qr^T
  unsigned short* Wt_uq  = w16 + 51118080;      //    786,432
  unsigned short* Wt_qr  = w16 + 51904512;      //    262,144 (= WtF2 + 1536*512)
  unsigned short* Wt_out = w16 + 52166656;      //  4,194,304
  (void)Wt_qr;

  dim3 blk256(256), blk512(512);
  const float qscale = 0.08838834764831845f * LOG2E;  // 1/sqrt(128)*log2(e)

  // prep: h f2bf (8192 blocks) + all 8 weight transposes (9984 tiles)
  TTab tab;
  tab.e[0] = mktent(W_dkv, Wt_dkv, E_, C_,       1024, 16);
  tab.e[1] = mktent(W_dq,  Wt_dq,  E_, C_,       1024, 16);
  tab.e[2] = mktent(W_kr,  Wt_kr,  E_, H_ * DR_, 1024, 16);
  tab.e[3] = mktent(W_uk,  Wt_uk,  C_, H_ * SP_,  768, 48);
  tab.e[4] = mktent(W_uv,  Wt_uv,  C_, H_ * DH_, 1024, 64);
  tab.e[5] = mktent(W_uq,  Wt_uq,  C_, H_ * SP_,  768, 48);
  tab.e[6] = mktent(W_qr,  w16 + 51904512, C_, H_ * DR_,  256, 16);
  tab.e[7] = mktent(W_out, Wt_out, E_, E_,       4096, 64);
  prep_kernel<<<18176, blk256, 0, stream>>>(h, h_bf, tab);

  // fused projection 1: [c_kv | c_q | k_rot] = h @ [W_dkv|W_dq|W_kr]
  // kr segment applies RoPE in-epilogue and writes fp32 k_rot to d_out.
  mfma_gemm<<<dim3(1536 / 128, M_ / 128), blk512, 0, stream>>>(
      h_bf, Wt_dkv,
      mkseg(out_ckv, ckv_bf, b_dkv, nullptr, C_, C_, C_, 0, 0, 0, 1.f, 0, nullptr),
      mkseg(nullptr, cq_bf,  b_dq,  nullptr, C_, C_, C_, 0, 512, 0, 1.f, 0, nullptr),
      mkseg(nullptr, k_bf,   b_kr,  nullptr, 2048, DR_, DH_, SP_, 1024, 0, 1.f,
            1, out_krot),
      E_);

  // fused K=512 trio: uk -> k_bf | V^T -> vt_bf | proj2 -> q_bf (qr RoPE'd)
  fused_gemm3<<<1408, blk512, 0, stream>>>(
      ckv_bf, cq_bf, Wt_uk, Wt_uv, Wt_uq, k_bf, vt_bf, q_bf,
      b_uk, b_uv, b_uq, b_qr, qscale);

  // merged-pair flash attention: grid = B*H*16 = 512, XCD+complementary map
  attn_kernel<<<B_ * H_ * 16, blk256, 0, stream>>>(q_bf, k_bf, vt_bf, ao_bf);

  // out = ao @ W_out + b  (fp32 -> d_out region 0)
  mfma_gemm<<<dim3(E_ / 128, M_ / 128), blk512, 0, stream>>>(
      ao_bf, Wt_out,
      mkseg(out, nullptr, b_out, nullptr, E_, E_, E_, 0, 0, 0, 1.f, 0, nullptr),
      segnone(), segnone(), E_);
}

// Round 9
// 343.299 us; speedup vs baseline: 1.0570x; 1.0570x over previous
//
#include <hip/hip_runtime.h>
#include <hip/hip_bf16.h>

// MLA forward. Storage fp32 in/out; internal pipeline bf16 MFMA, fp32 accum.
// R9 changes vs R8 (362.9us; best R7 = 353.7us):
//  - GEMM: revert to R7 4-wave/256-thr body (R8's 8-wave halved per-wave
//    MFMA per barrier phase -> regression). BK=64 via paired [128][32]
//    sub-buffers for the K=2048 GEMMs (proj1, out-proj): barriers halve
//    64->32, identical read layout + MFMA order (bit-identical outputs).
//    fused3 (K=512) stays BK=32 to keep ~4 blocks/CU.
//  - RoPE fusion kept (R8-verified), ported to 4-wave epilogue, using
//    __sinf/__cosf (err ~1e-6 << tol) to avoid trig stragglers. 5 launches.
//  - attn unchanged from R7 (verified 73.5us).
#define B_   2
#define S_   2048
#define E_   2048
#define H_   16
#define DH_  128
#define DR_  32
#define SP_  96
#define C_   512
#define M_   (B_ * S_)   // 4096 rows

#define LOG2E 1.4426950408889634f

typedef __attribute__((ext_vector_type(8))) short short8;
typedef __attribute__((ext_vector_type(4))) float floatx4;

__device__ __forceinline__ float bfu(unsigned short u) {
  return __uint_as_float((unsigned)u << 16);
}
__device__ __forceinline__ unsigned short f2bf(float f) {
  unsigned u = __float_as_uint(f);
  return (unsigned short)((u + 0x7fff + ((u >> 16) & 1)) >> 16);  // RNE
}

// async global->LDS, 16B per lane. LDS dest: wave-uniform base + lane*16.
__device__ __forceinline__ void gload16(const void* g, void* l) {
  __builtin_amdgcn_global_load_lds(
      (const __attribute__((address_space(1))) void*)g,
      (__attribute__((address_space(3))) void*)l, 16, 0, 0);
}

// ---------- prep: fp32->bf16 h convert + all 8 weight transposes ----------
struct TEnt { const float* W; unsigned short* Wt; int K, N, ntiles, nx; };
struct TTab { TEnt e[8]; };

__global__ __launch_bounds__(256) void prep_kernel(
    const float* __restrict__ hsrc, unsigned short* __restrict__ hdst,
    TTab tab) {
  if (blockIdx.x < 8192) {  // f2bf path (block-uniform branch)
    size_t i = ((size_t)blockIdx.x * 256 + threadIdx.x) * 4;
    float4 v = *(const float4*)(hsrc + i);
    ushort4 w;
    w.x = f2bf(v.x); w.y = f2bf(v.y); w.z = f2bf(v.z); w.w = f2bf(v.w);
    *(ushort4*)(hdst + i) = w;
    return;
  }
  __shared__ unsigned short T[32][33];
  int rem = blockIdx.x - 8192;
  const float* W = nullptr; unsigned short* Wt = nullptr;
  int K = 0, N = 0, nx = 1;
  bool done = false;
#pragma unroll
  for (int j = 0; j < 8; j++) {   // constant-index select (stays in SGPRs)
    if (!done) {
      if (rem < tab.e[j].ntiles) {
        W = tab.e[j].W; Wt = tab.e[j].Wt;
        K = tab.e[j].K; N = tab.e[j].N; nx = tab.e[j].nx;
        done = true;
      } else {
        rem -= tab.e[j].ntiles;
      }
    }
  }
  int n0 = (rem % nx) * 32, k0 = (rem / nx) * 32;
  int t = threadIdx.x, lane = t & 31, grp = t >> 5;
#pragma unroll
  for (int p = 0; p < 4; p++) {
    int k = p * 8 + grp;
    T[lane][k] = f2bf(W[(size_t)(k0 + k) * N + n0 + lane]);
  }
  __syncthreads();
#pragma unroll
  for (int p = 0; p < 4; p++) {
    int n = p * 8 + grp;
    Wt[(size_t)(n0 + n) * K + k0 + lane] = T[n][lane];
  }
}

// ---------- bf16 MFMA GEMM core: 4 waves, 128^2 tile, 2-phase pipeline ----------
struct Seg {
  float* outF;
  unsigned short* outB;
  const float* bias;    // indexed by n_local
  const float* biasM;   // indexed by m (overrides bias)
  float* krotF;         // rope==1: fp32 k_rot out (idx m*512 + nl)
  int orow, chunk, gstride, obase, nstart, ileave, rope;
  float oscale;
};

template <bool BK64>
__device__ __forceinline__ void gemm_body(
    const unsigned short* __restrict__ A, const unsigned short* __restrict__ W,
    int K, int bm, int bn, const Seg& sg) {
  // BK64: each buffer holds a 64-K tile as TWO [128][32] row-major halves
  // (half b at +4096 shorts). Read/MFMA order identical to BK32.
  __shared__ unsigned short As0[BK64 ? 128 * 64 : 128 * 32];
  __shared__ unsigned short Bs0[BK64 ? 128 * 64 : 128 * 32];
  __shared__ unsigned short As1[BK64 ? 128 * 64 : 128 * 32];
  __shared__ unsigned short Bs1[BK64 ? 128 * 64 : 128 * 32];
  int tid = threadIdx.x;
  int lane = tid & 63, wave = tid >> 6;
  int l16 = lane & 15, quad = lane >> 4;
  int wm = (wave & 1) * 64, wn = (wave >> 1) * 64;

  floatx4 acc[4][4];
#pragma unroll
  for (int mt = 0; mt < 4; mt++)
#pragma unroll
    for (int nt = 0; nt < 4; nt++) acc[mt][nt] = (floatx4){0.f, 0.f, 0.f, 0.f};

  // staging: 8 chunks of 1KB per operand per 32-half; wave w owns 2w, 2w+1.
  int c0 = wave * 2, c1 = c0 + 1;
  int srow = lane >> 2, scol = (lane & 3) * 8;
  const unsigned short* Ag0 = A + (size_t)(bm + c0 * 16 + srow) * K + scol;
  const unsigned short* Ag1 = A + (size_t)(bm + c1 * 16 + srow) * K + scol;
  const unsigned short* Bg0 = W + (size_t)(bn + c0 * 16 + srow) * K + scol;
  const unsigned short* Bg1 = W + (size_t)(bn + c1 * 16 + srow) * K + scol;

#define GSTAGE(kk, Asb, Bsb) do {            \
    gload16(Ag0 + (kk), &Asb[c0 * 512]);     \
    gload16(Ag1 + (kk), &Asb[c1 * 512]);     \
    gload16(Bg0 + (kk), &Bsb[c0 * 512]);     \
    gload16(Bg1 + (kk), &Bsb[c1 * 512]); } while (0)

#define GSTAGE64(kk, Asb, Bsb) do {                 \
    gload16(Ag0 + (kk),      &Asb[c0 * 512]);       \
    gload16(Ag1 + (kk),      &Asb[c1 * 512]);       \
    gload16(Bg0 + (kk),      &Bsb[c0 * 512]);       \
    gload16(Bg1 + (kk),      &Bsb[c1 * 512]);       \
    gload16(Ag0 + (kk) + 32, &Asb[4096 + c0 * 512]);\
    gload16(Ag1 + (kk) + 32, &Asb[4096 + c1 * 512]);\
    gload16(Bg0 + (kk) + 32, &Bsb[4096 + c0 * 512]);\
    gload16(Bg1 + (kk) + 32, &Bsb[4096 + c1 * 512]); } while (0)

#define GCOMPUTE(Ap, Bp) do {                                              \
    const unsigned short* Asb = (Ap);                                      \
    const unsigned short* Bsb = (Bp);                                      \
    short8 af[4], bfv[4];                                                  \
    _Pragma("unroll")                                                      \
    for (int mt = 0; mt < 4; mt++)                                         \
      af[mt] = *(const short8*)&Asb[(wm + mt * 16 + l16) * 32 + quad * 8]; \
    _Pragma("unroll")                                                      \
    for (int nt = 0; nt < 4; nt++)                                         \
      bfv[nt] = *(const short8*)&Bsb[(wn + nt * 16 + l16) * 32 + quad * 8];\
    _Pragma("unroll")                                                      \
    for (int mt = 0; mt < 4; mt++)                                         \
      _Pragma("unroll")                                                    \
      for (int nt = 0; nt < 4; nt++)                                       \
        acc[mt][nt] = __builtin_amdgcn_mfma_f32_16x16x32_bf16(             \
            af[mt], bfv[nt], acc[mt][nt], 0, 0, 0); } while (0)

  if constexpr (BK64) {
    // K % 128 == 0 at both call sites (K = 2048).
    GSTAGE64(0, As0, Bs0);
    __syncthreads();
    for (int k0 = 0; k0 < K; k0 += 128) {
      GSTAGE64(k0 + 64, As1, Bs1);
      GCOMPUTE(&As0[0], &Bs0[0]);
      GCOMPUTE(&As0[4096], &Bs0[4096]);
      __syncthreads();
      if (k0 + 128 < K) GSTAGE64(k0 + 128, As0, Bs0);
      GCOMPUTE(&As1[0], &Bs1[0]);
      GCOMPUTE(&As1[4096], &Bs1[4096]);
      __syncthreads();
    }
  } else {
    GSTAGE(0, As0, Bs0);
    __syncthreads();
    for (int k0 = 0; k0 < K; k0 += 64) {
      GSTAGE(k0 + 32, As1, Bs1);
      GCOMPUTE(&As0[0], &Bs0[0]);
      __syncthreads();
      if (k0 + 64 < K) GSTAGE(k0 + 64, As0, Bs0);
      GCOMPUTE(&As1[0], &Bs1[0]);
      __syncthreads();
    }
  }
#undef GSTAGE
#undef GSTAGE64
#undef GCOMPUTE

  // C/D layout: D[row=quad*4+r][col=l16]
#pragma unroll
  for (int mt = 0; mt < 4; mt++) {
    int m0 = bm + wm + mt * 16 + quad * 4;
    float bm4[4] = {0.f, 0.f, 0.f, 0.f};
    if (sg.biasM) {
#pragma unroll
      for (int r = 0; r < 4; r++) bm4[r] = sg.biasM[m0 + r];
    }
#pragma unroll
    for (int nt = 0; nt < 4; nt++) {
      int n = bn + wn + nt * 16 + l16;
      int nl = n - sg.nstart;
      float bv = sg.biasM ? 0.f : sg.bias[nl];
      int ncol = sg.obase + (nl / sg.chunk) * sg.gstride + (nl % sg.chunk);
      if (sg.ileave)  // 32-wide k-interleave (attn V: phys 2k,2k+1 = k, k+16)
        ncol = (ncol & ~31) | ((ncol & 15) << 1) | ((ncol >> 4) & 1);
      bool rot_half = sg.rope && ((nl & 31) < 16);  // wave-uniform per nt
#pragma unroll
      for (int r = 0; r < 4; r++) {
        float val = (acc[mt][nt][r] + (sg.biasM ? bm4[r] : bv)) * sg.oscale;
        if (rot_half) {
          // rotation pair (j, j+8): partner at lane l16^8, same nt block
          int j = l16 & 7;
          int srw = (m0 + r) & (S_ - 1);
          float ang = ((float)srw / 40.0f) *
                      exp2f(-1.6609640474436813f * (float)j);
          float cc = __cosf(ang), ss = __sinf(ang);
          float part = __shfl_xor(val, 8);
          val = (l16 < 8) ? (val * cc - part * ss) : (val * cc + part * ss);
        }
        if (sg.rope == 1 && sg.krotF)
          sg.krotF[(size_t)(m0 + r) * (H_ * DR_) + nl] = val;
        size_t idx = (size_t)(m0 + r) * sg.orow + ncol;
        if (sg.outF) sg.outF[idx] = val;
        if (sg.outB) sg.outB[idx] = f2bf(val);
      }
    }
  }
}

// generic multi-segment GEMM (proj1, out-proj)
template <bool BK64>
__global__ __launch_bounds__(256) void mfma_gemm(
    const unsigned short* __restrict__ A, const unsigned short* __restrict__ Wt,
    Seg s0, Seg s1, Seg s2, int K) {
  // XCD swizzle (bijective; nwg % 8 == 0 at every call site)
  int gx = gridDim.x;
  int nwg = gx * gridDim.y;
  int flat = blockIdx.y * gx + blockIdx.x;
  int w = (flat & 7) * (nwg >> 3) + (flat >> 3);
  int by = w / gx, bx = w - by * gx;
  int bm = by * 128, bn = bx * 128;
  Seg sg = (bn >= s2.nstart) ? s2 : ((bn >= s1.nstart) ? s1 : s0);
  gemm_body<BK64>(A, Wt, K, bm, bn, sg);
}

// fused K=512 GEMM trio: uk (384 blk) | V^T (512 blk) | proj2 (512 blk)
__global__ __launch_bounds__(256) void fused_gemm3(
    const unsigned short* __restrict__ ckv, const unsigned short* __restrict__ cq,
    const unsigned short* __restrict__ wuk, const unsigned short* __restrict__ wuv,
    const unsigned short* __restrict__ wuq,
    unsigned short* __restrict__ kbf, unsigned short* __restrict__ vtbf,
    unsigned short* __restrict__ qbf,
    const float* __restrict__ b_uk, const float* __restrict__ b_uv,
    const float* __restrict__ b_uq, const float* __restrict__ b_qr,
    float qscale) {
  int flat = blockIdx.x;                      // 0..1407
  int w = (flat & 7) * 176 + (flat >> 3);     // XCD swizzle (1408/8 = 176)
  const unsigned short* A; const unsigned short* W;
  int bm, bn;
  Seg sg;
  sg.outF = nullptr; sg.oscale = 1.f; sg.ileave = 0; sg.nstart = 0;
  sg.rope = 0; sg.krotF = nullptr;
  if (w < 384) {              // uk: c_kv @ W_uk -> k_bf (head remap)
    int by = w / 12, bx = w - by * 12;
    bm = by * 128; bn = bx * 128;
    A = ckv; W = wuk;
    sg.outB = kbf; sg.bias = b_uk; sg.biasM = nullptr;
    sg.orow = 2048; sg.chunk = SP_; sg.gstride = DH_; sg.obase = 0;
  } else if (w < 896) {       // V^T: W_uv^T @ c_kv^T -> vt_bf (interleaved)
    int w2 = w - 384;
    int by = w2 >> 5, bx = w2 & 31;
    bm = by * 128; bn = bx * 128;
    A = wuv; W = ckv;
    sg.outB = vtbf; sg.bias = nullptr; sg.biasM = b_uv;
    sg.orow = M_; sg.chunk = M_; sg.gstride = M_; sg.obase = 0; sg.ileave = 1;
  } else {                    // proj2: c_q @ [W_uq|W_qr] -> q_bf, pre-scaled
    int w3 = w - 896;
    int by = w3 >> 4, bx = w3 & 15;
    bm = by * 128; bn = bx * 128;
    A = cq; W = wuq;
    sg.outB = qbf; sg.biasM = nullptr; sg.orow = 2048; sg.oscale = qscale;
    if (bn >= 1536) {
      sg.bias = b_qr; sg.chunk = DR_; sg.gstride = DH_; sg.obase = SP_;
      sg.nstart = 1536; sg.rope = 2;  // fused RoPE on q_rot
    } else {
      sg.bias = b_uq; sg.chunk = SP_; sg.gstride = DH_; sg.obase = 0;
    }
  }
  gemm_body<false>(A, W, 512, bm, bn, sg);
}

// ---------- flash attention: merged pair, KVBLK=64, swizzled LDS ----------
// (R7 kernel verbatim.)
#define PST 72
__global__ __launch_bounds__(256, 2) void attn_kernel(
    const unsigned short* __restrict__ qf, const unsigned short* __restrict__ kf,
    const unsigned short* __restrict__ vt, unsigned short* __restrict__ ao) {
  __shared__ unsigned short Ks[2][64 * 128];   // row=k (256B), 16 slots
  __shared__ unsigned short Vs[2][128 * 64];   // row=d (128B), 8 slots
  __shared__ unsigned short Ps[4][16 * PST];

  int bid0 = blockIdx.x;            // 0..511
  int xcd  = bid0 & 7;
  int idx  = bid0 >> 3;             // 0..63 within XCD
  int r_   = idx >> 5;              // dispatch round (fills CUs once each)
  int q_   = idx & 31;
  int bh   = xcd * 4 + (q_ >> 3);   // 4 bh per XCD
  int jp   = r_ ? (15 - (q_ & 7)) : (q_ & 7);  // complementary per CU
  int h    = bh & 15;
  int b    = bh >> 4;
  int jjh  = 31 - jp;               // hi q-tile
  int jjl  = jp;                    // lo q-tile
  int q0h  = jjh << 6, q0l = jjl << 6;
  int nchunks = jjh + 1;            // 64-k chunks (17..32)

  int tid  = threadIdx.x;
  int wave = tid >> 6;
  int lane = tid & 63;
  int l16  = lane & 15;
  int quad = lane >> 4;
  int x7   = l16 & 7;

  // ---- staging maps (per thread: 4x16B K + 4x16B V per chunk) ----
  int krow = tid >> 2;              // 0..63
  int kst  = (tid & 3) * 4;         // starting 16B slot of 16
  int vrow = tid >> 1;              // 0..127
  int vst  = (tid & 1) * 4;         // starting 16B slot of 8
  const unsigned short* kg =
      kf + ((size_t)(b * S_ + krow)) * 2048 + h * 128 + kst * 8;
  const unsigned short* vg =
      vt + ((size_t)(h * 128 + vrow)) * 4096 + b * 2048 + vst * 8;
  // swizzled LDS write offsets (shorts)
  int kwl[4], vwl[4];
#pragma unroll
  for (int i = 0; i < 4; i++) {
    kwl[i] = krow * 128 + (((kst + i) ^ (krow & 7)) * 8);
    vwl[i] = vrow * 64  + (((vst + i) ^ (vrow & 7)) * 8);
  }

  // ---- Q fragments for both sides (pre-scaled in projection epilogue) ----
  short8 qfh[4], qfl[4];
  {
    const unsigned short* qb =
        qf + ((size_t)(b * S_ + q0h + wave * 16 + l16)) * 2048 + h * 128 + quad * 8;
#pragma unroll
    for (int c = 0; c < 4; c++) qfh[c] = *(const short8*)(qb + c * 32);
  }
  {
    const unsigned short* qb =
        qf + ((size_t)(b * S_ + q0l + wave * 16 + l16)) * 2048 + h * 128 + quad * 8;
#pragma unroll
    for (int c = 0; c < 4; c++) qfl[c] = *(const short8*)(qb + c * 32);
  }

  floatx4 OaccH[8], OaccL[8];
#pragma unroll
  for (int dt = 0; dt < 8; dt++) {
    OaccH[dt] = (floatx4){0.f, 0.f, 0.f, 0.f};
    OaccL[dt] = (floatx4){0.f, 0.f, 0.f, 0.f};
  }
  float lpH[4] = {0.f, 0.f, 0.f, 0.f};
  float lpL[4] = {0.f, 0.f, 0.f, 0.f};
  int qgh = q0h + wave * 16;        // base q row of this wave, hi side
  int qgl = q0l + wave * 16;

  // one side's compute vs staged chunk t in buf `cur`
#define SCOMPUTE(QF, OC, LP, QG, DIAG) do {                                   \
    const unsigned short* Kc = Ks[cur];                                       \
    const unsigned short* Vc = Vs[cur];                                       \
    floatx4 sv[4];                                                            \
    _Pragma("unroll")                                                         \
    for (int nt = 0; nt < 4; nt++) sv[nt] = (floatx4){0.f, 0.f, 0.f, 0.f};    \
    __builtin_amdgcn_s_setprio(1);                                            \
    _Pragma("unroll")                                                         \
    for (int nt = 0; nt < 4; nt++)                                            \
      _Pragma("unroll")                                                       \
      for (int c = 0; c < 4; c++) {                                           \
        short8 kfr = *(const short8*)&Kc[(nt * 16 + l16) * 128 +              \
                                         ((4 * c + quad) ^ x7) * 8];          \
        sv[nt] = __builtin_amdgcn_mfma_f32_16x16x32_bf16(QF[c], kfr, sv[nt],  \
                                                         0, 0, 0);            \
      }                                                                       \
    __builtin_amdgcn_s_setprio(0);                                            \
    unsigned short* P = Ps[wave];                                             \
    _Pragma("unroll")                                                         \
    for (int ks = 0; ks < 2; ks++)                                            \
      _Pragma("unroll")                                                       \
      for (int r = 0; r < 4; r++) {                                           \
        float p0 = exp2f(fminf(sv[2 * ks][r], 80.f));                         \
        float p1 = exp2f(fminf(sv[2 * ks + 1][r], 80.f));                     \
        if (DIAG) {                                                           \
          int q_r = QG + quad * 4 + r;                                        \
          int kc0 = kt0 + ks * 32 + l16;                                      \
          if (kc0 > q_r)      p0 = 0.f;                                       \
          if (kc0 + 16 > q_r) p1 = 0.f;                                       \
        }                                                                     \
        unsigned pk;                                                          \
        asm("v_cvt_pk_bf16_f32 %0, %1, %2" : "=v"(pk) : "v"(p0), "v"(p1));    \
        *(unsigned*)&P[(quad * 4 + r) * PST + ks * 32 + 2 * l16] = pk;        \
        LP[r] += p0 + p1;                                                     \
      }                                                                       \
    short8 pf0 = *(const short8*)&P[l16 * PST + quad * 8];                    \
    short8 pf1 = *(const short8*)&P[l16 * PST + 32 + quad * 8];               \
    __builtin_amdgcn_s_setprio(1);                                            \
    _Pragma("unroll")                                                         \
    for (int dt = 0; dt < 8; dt++) {                                          \
      short8 vf0 = *(const short8*)&Vc[(dt * 16 + l16) * 64 +                 \
                                       ((quad) ^ x7) * 8];                    \
      OC[dt] = __builtin_amdgcn_mfma_f32_16x16x32_bf16(pf0, vf0, OC[dt],      \
                                                       0, 0, 0);              \
      short8 vf1 = *(const short8*)&Vc[(dt * 16 + l16) * 64 +                 \
                                       ((4 + quad) ^ x7) * 8];                \
      OC[dt] = __builtin_amdgcn_mfma_f32_16x16x32_bf16(pf1, vf1, OC[dt],      \
                                                       0, 0, 0);              \
    }                                                                         \
    __builtin_amdgcn_s_setprio(0);                                            \
  } while (0)

  // ---- prologue: chunk 0 -> buf0; chunk 1 -> regs ----
  short8 kr[4], vr[4];
#pragma unroll
  for (int i = 0; i < 4; i++) {
    kr[i] = *(const short8*)(kg + i * 8);
    vr[i] = *(const short8*)(vg + i * 8);
  }
#pragma unroll
  for (int i = 0; i < 4; i++) {
    *(short8*)&Ks[0][kwl[i]] = kr[i];
    *(short8*)&Vs[0][vwl[i]] = vr[i];
  }
#pragma unroll
  for (int i = 0; i < 4; i++) {       // chunk 1 (nchunks >= 17)
    kr[i] = *(const short8*)(kg + 131072 + i * 8);
    vr[i] = *(const short8*)(vg + 64 + i * 8);
  }
  __syncthreads();

  int cur = 0;
  for (int t = 0; t < nchunks; t++) {
    // write chunk t+1 from regs into the other buffer
#pragma unroll
    for (int i = 0; i < 4; i++) {
      *(short8*)&Ks[cur ^ 1][kwl[i]] = kr[i];
      *(short8*)&Vs[cur ^ 1][vwl[i]] = vr[i];
    }
    // prefetch chunk t+2 (clamped)
    {
      int tf = (t + 2 < nchunks) ? t + 2 : nchunks - 1;
      const unsigned short* ksrc = kg + (size_t)tf * 131072;
      const unsigned short* vsrc = vg + tf * 64;
#pragma unroll
      for (int i = 0; i < 4; i++) {
        kr[i] = *(const short8*)(ksrc + i * 8);
        vr[i] = *(const short8*)(vsrc + i * 8);
      }
    }
    int kt0 = t << 6;
    SCOMPUTE(qfh, OaccH, lpH, qgh, (t == jjh));
    if (t <= jjl) SCOMPUTE(qfl, OaccL, lpL, qgl, (t == jjl));
    __syncthreads();
    cur ^= 1;
  }
#undef SCOMPUTE

  // ---- epilogue: l-reduction + store, both sides ----
#pragma unroll
  for (int side = 0; side < 2; side++) {
    floatx4* OC = side ? OaccL : OaccH;
    float*   LP = side ? lpL : lpH;
    int qg = (side ? qgl : qgh) + quad * 4;
    float linv[4];
#pragma unroll
    for (int r = 0; r < 4; r++) {
      float ls = LP[r];
#pragma unroll
      for (int sh = 1; sh < 16; sh <<= 1) ls += __shfl_xor(ls, sh);
      linv[r] = 1.0f / ls;
    }
#pragma unroll
    for (int r = 0; r < 4; r++) {
      unsigned short* dst =
          ao + ((size_t)(b * S_ + qg + r)) * 2048 + h * 128 + l16;
#pragma unroll
      for (int dt = 0; dt < 8; dt++) dst[dt * 16] = f2bf(OC[dt][r] * linv[r]);
    }
  }
}

static inline Seg mkseg(float* oF, unsigned short* oB, const float* bias,
                        const float* biasM, int orow, int chunk, int gstride,
                        int obase, int nstart, int ileave, float oscale,
                        int rope, float* krotF) {
  Seg s;
  s.outF = oF; s.outB = oB; s.bias = bias; s.biasM = biasM; s.krotF = krotF;
  s.orow = orow; s.chunk = chunk; s.gstride = gstride;
  s.obase = obase; s.nstart = nstart; s.ileave = ileave; s.rope = rope;
  s.oscale = oscale;
  return s;
}
static inline Seg segnone() {
  return mkseg(nullptr, nullptr, nullptr, nullptr, 1, 1, 1, 0, 0x7fffffff,
               0, 1.f, 0, nullptr);
}
static inline TEnt mktent(const float* W, unsigned short* Wt, int K, int N,
                          int ntiles, int nx) {
  TEnt e;
  e.W = W; e.Wt = Wt; e.K = K; e.N = N; e.ntiles = ntiles; e.nx = nx;
  return e;
}

extern "C" void kernel_launch(void* const* d_in, const int* in_sizes, int n_in,
                              void* d_out, int out_size, void* d_ws, size_t ws_size,
                              hipStream_t stream) {
  const float* h     = (const float*)d_in[0];
  const float* W_dkv = (const float*)d_in[1];
  const float* b_dkv = (const float*)d_in[2];
  const float* W_dq  = (const float*)d_in[3];
  const float* b_dq  = (const float*)d_in[4];
  const float* W_uk  = (const float*)d_in[5];
  const float* b_uk  = (const float*)d_in[6];
  const float* W_uv  = (const float*)d_in[7];
  const float* b_uv  = (const float*)d_in[8];
  const float* W_uq  = (const float*)d_in[9];
  const float* b_uq  = (const float*)d_in[10];
  const float* W_qr  = (const float*)d_in[11];
  const float* b_qr  = (const float*)d_in[12];
  const float* W_kr  = (const float*)d_in[13];
  const float* b_kr  = (const float*)d_in[14];
  const float* W_out = (const float*)d_in[15];
  const float* b_out = (const float*)d_in[16];

  float* out      = (float*)d_out;
  float* out_ckv  = out + (size_t)M_ * E_;
  float* out_krot = out_ckv + (size_t)M_ * C_;

  unsigned short* w16 = (unsigned short*)d_ws;
  unsigned short* h_bf   = w16;                 //  8,388,608
  unsigned short* q_bf   = w16 + 8388608;       //  8,388,608
  unsigned short* k_bf   = w16 + 16777216;      //  8,388,608
  unsigned short* vt_bf  = w16 + 25165824;      //  8,388,608  (V^T, s interleaved)
  unsigned short* ao_bf  = w16 + 33554432;      //  8,388,608
  unsigned short* ckv_bf = w16 + 41943040;      //  2,097,152
  unsigned short* cq_bf  = w16 + 44040192;      //  2,097,152
  // fused weight 1: rows [0,512)=W_dkv^T, [512,1024)=W_dq^T, [1024,1536)=W_kr^T
  unsigned short* Wt_dkv = w16 + 46137344;      //  1,048,576
  unsigned short* Wt_dq  = w16 + 47185920;      //  1,048,576 (= WtF1 + 512*2048)
  unsigned short* Wt_kr  = w16 + 48234496;      //  1,048,576 (= WtF1 + 1024*2048)
  unsigned short* Wt_uk  = w16 + 49283072;      //    786,432
  unsigned short* Wt_uv  = w16 + 50069504;      //  1,048,576
  // fused weight 2: rows [0,1536)=W_uq^T, [1536,2048)=W_qr^T
  unsigned short* Wt_uq  = w16 + 51118080;      //    786,432
  unsigned short* Wt_qr  = w16 + 51904512;      //    262,144 (= WtF2 + 1536*512)
  unsigned short* Wt_out = w16 + 52166656;      //  4,194,304
  (void)Wt_qr;

  dim3 blk256(256);
  const float qscale = 0.08838834764831845f * LOG2E;  // 1/sqrt(128)*log2(e)

  // prep: h f2bf (8192 blocks) + all 8 weight transposes (9984 tiles)
  TTab tab;
  tab.e[0] = mktent(W_dkv, Wt_dkv, E_, C_,       1024, 16);
  tab.e[1] = mktent(W_dq,  Wt_dq,  E_, C_,       1024, 16);
  tab.e[2] = mktent(W_kr,  Wt_kr,  E_, H_ * DR_, 1024, 16);
  tab.e[3] = mktent(W_uk,  Wt_uk,  C_, H_ * SP_,  768, 48);
  tab.e[4] = mktent(W_uv,  Wt_uv,  C_, H_ * DH_, 1024, 64);
  tab.e[5] = mktent(W_uq,  Wt_uq,  C_, H_ * SP_,  768, 48);
  tab.e[6] = mktent(W_qr,  w16 + 51904512, C_, H_ * DR_,  256, 16);
  tab.e[7] = mktent(W_out, Wt_out, E_, E_,       4096, 64);
  prep_kernel<<<18176, blk256, 0, stream>>>(h, h_bf, tab);

  // fused projection 1: [c_kv | c_q | k_rot] = h @ [W_dkv|W_dq|W_kr]
  // kr segment applies RoPE in-epilogue and writes fp32 k_rot to d_out.
  mfma_gemm<true><<<dim3(1536 / 128, M_ / 128), blk256, 0, stream>>>(
      h_bf, Wt_dkv,
      mkseg(out_ckv, ckv_bf, b_dkv, nullptr, C_, C_, C_, 0, 0, 0, 1.f, 0, nullptr),
      mkseg(nullptr, cq_bf,  b_dq,  nullptr, C_, C_, C_, 0, 512, 0, 1.f, 0, nullptr),
      mkseg(nullptr, k_bf,   b_kr,  nullptr, 2048, DR_, DH_, SP_, 1024, 0, 1.f,
            1, out_krot),
      E_);

  // fused K=512 trio: uk -> k_bf | V^T -> vt_bf | proj2 -> q_bf (qr RoPE'd)
  fused_gemm3<<<1408, blk256, 0, stream>>>(
      ckv_bf, cq_bf, Wt_uk, Wt_uv, Wt_uq, k_bf, vt_bf, q_bf,
      b_uk, b_uv, b_uq, b_qr, qscale);

  // merged-pair flash attention: grid = B*H*16 = 512, XCD+complementary map
  attn_kernel<<<B_ * H_ * 16, blk256, 0, stream>>>(q_bf, k_bf, vt_bf, ao_bf);

  // out = ao @ W_out + b  (fp32 -> d_out region 0)
  mfma_gemm<true><<<dim3(E_ / 128, M_ / 128), blk256, 0, stream>>>(
      ao_bf, Wt_out,
      mkseg(out, nullptr, b_out, nullptr, E_, E_, E_, 0, 0, 0, 1.f, 0, nullptr),
      segnone(), segnone(), E_);
}